// Round 2
// baseline (657.129 us; speedup 1.0000x reference)
//
#include <hip/hip_runtime.h>

// Problem constants
#define PAD_ID 0
#define NTOK   16384          // B*L = 16*1024
#define DIM    768
#define KLAT   5000
#define KPAD   5024           // 157*32, zero-padded latent rows
#define NSTEP  157            // 5024/32
#define TOKB   32             // tokens per block (512 blocks -> 2 blocks/CU)

// Unified LDS latent image (per 32-lat tile):
//   elem(lat, d) at  dG*560 + slot*16 + (d&15),  dG = d>>4,
//   slot = 9*(lat>>3) + (lat&7)   (35-slot pitch; slots 8,17,26 are pad)
// The 9-row pitch rotates each 8-lat group by +32B so ds_read_b64_tr_b16
// (fixed 32B element stride) is bank-conflict-free across the 4 quads,
// while A-frags stay plain ds_read_b128 at full throughput.
#define TILE_SH 26880         // shorts per padded tile (48 dG * 560) = 53760 B
#define TCH     3360          // 16B chunks per tile

typedef float f32x4 __attribute__((ext_vector_type(4)));
typedef __bf16 bf16x8 __attribute__((ext_vector_type(8)));
typedef unsigned int u32x2 __attribute__((ext_vector_type(2)));

__device__ __forceinline__ unsigned int f2bf(float f) {
    unsigned int u = __float_as_uint(f);
    u += 0x7fffu + ((u >> 16) & 1u);   // RNE
    return u >> 16;
}
__device__ __forceinline__ float bf2f(unsigned short h) {
    return __uint_as_float(((unsigned int)h) << 16);
}
__device__ __forceinline__ void async_cp16(const unsigned short* g, unsigned short* l) {
    __builtin_amdgcn_global_load_lds(
        (const __attribute__((address_space(1))) unsigned int*)g,
        (__attribute__((address_space(3))) unsigned int*)l, 16, 0, 0);
}

// ---------------------------------------------------------------------------
// Kernel 0: latent -> latb, bf16, unified padded image (see above).
// Pad slots (jj==8) and rows >= KLAT are zero.
// ---------------------------------------------------------------------------
__global__ __launch_bounds__(256) void cvt_latU(const float* __restrict__ latent,
                                                unsigned short* __restrict__ latb) {
    int c = blockIdx.x * 256 + threadIdx.x;          // one 16B chunk (8 elems)
    if (c >= NSTEP * TCH) return;
    int t  = c / TCH;  int r  = c - t * TCH;
    int dG = r / 70;   int cc = r - dG * 70;         // 70 chunks per subtile
    int slot = cc >> 1; int ln0 = (cc & 1) * 8;
    int q = slot / 9;  int jj = slot - q * 9;        // jj==8 -> pad row
    int row = t * 32 + q * 8 + jj;
    uint4 o = make_uint4(0u, 0u, 0u, 0u);
    if (jj < 8 && row < KLAT) {
        const float* src = latent + (long)row * DIM + dG * 16 + ln0;
        float4 v0 = *(const float4*)src;
        float4 v1 = *(const float4*)(src + 4);
        o.x = f2bf(v0.x) | (f2bf(v0.y) << 16);
        o.y = f2bf(v0.z) | (f2bf(v0.w) << 16);
        o.z = f2bf(v1.x) | (f2bf(v1.y) << 16);
        o.w = f2bf(v1.z) | (f2bf(v1.w) << 16);
    }
    *(uint4*)(latb + (size_t)c * 8) = o;
}

// ---------------------------------------------------------------------------
// Kernel 1: lang_emb = tanh(masked-mean of char embeddings), stored bf16.
// ---------------------------------------------------------------------------
__global__ __launch_bounds__(192) void build_lang(const int* __restrict__ x,
                                                  const float* __restrict__ cemb,
                                                  unsigned short* __restrict__ langb) {
    int tok = blockIdx.x;
    int t = threadIdx.x;
    const int* xs = x + tok * 8;
    int ids[8]; int cnt = 0;
    #pragma unroll
    for (int c = 0; c < 8; ++c) { ids[c] = xs[c]; cnt += (ids[c] != PAD_ID); }
    float4 acc = make_float4(0.f, 0.f, 0.f, 0.f);
    #pragma unroll
    for (int c = 0; c < 8; ++c) {
        if (ids[c] != PAD_ID) {
            float4 v = *(const float4*)(cemb + (long)ids[c] * DIM + t * 4);
            acc.x += v.x; acc.y += v.y; acc.z += v.z; acc.w += v.w;
        }
    }
    float cntf = (float)max(cnt, 1);
    unsigned int u0 = f2bf(tanhf(acc.x / cntf)) | (f2bf(tanhf(acc.y / cntf)) << 16);
    unsigned int u1 = f2bf(tanhf(acc.z / cntf)) | (f2bf(tanhf(acc.w / cntf)) << 16);
    *(uint2*)(langb + tok * DIM + t * 4) = make_uint2(u0, u1);
}

// ---------------------------------------------------------------------------
// Kernel 2 (v3): single latent stream. Per step the 48KB(+pad) tile is DMA'd
// to LDS once; S-phase reads A-frags (ds_read_b128, conflict-free) and the
// O-phase B-frags are pulled from the SAME tile via ds_read_b64_tr_b16
// (HW transpose read, conflict-free in the 35-pitch image). latbT stream
// and its global bO loads are gone -> per-block traffic halves.
// tr reads complete (lgkmcnt(0)+sched_barrier, rule #18) BEFORE barrier1,
// so the next-tile DMA issued after barrier1 cannot clobber them.
// ---------------------------------------------------------------------------
__global__ __launch_bounds__(256, 2) void fused_sde(
        const int* __restrict__ x, const float* __restrict__ cemb,
        const unsigned short* __restrict__ langb,
        const unsigned short* __restrict__ latb,
        float* __restrict__ out) {
    __shared__ unsigned short sLat[TILE_SH];   // 53.76 KB padded image
    __shared__ unsigned short sP[TOKB * 40];   // P, row-padded (+8) for banks
    __shared__ float sL[2][TOKB];

    const int tid  = threadIdx.x;
    const int w    = tid >> 6;
    const int lane = tid & 63;
    const int lr   = lane & 15;      // A: lat-in-tile / B: d-low / tok for pA
    const int q    = lane >> 4;
    const int tt   = w & 1;          // token tile (0..1)
    const int lt   = w >> 1;         // lat tile within step (0..1)
    const int m0   = blockIdx.x * TOKB;

    // Q fragments (B-operand for S^T): token = m0 + tt*16 + lr
    uint4 qf[24];
    {
        const unsigned short* qr = langb + (m0 + tt * 16 + lr) * DIM;
        #pragma unroll
        for (int kf = 0; kf < 24; ++kf)
            qf[kf] = *(const uint4*)(qr + kf * 32 + q * 8);
    }

    f32x4 accO[2][12];
    #pragma unroll
    for (int mt = 0; mt < 2; ++mt)
        #pragma unroll
        for (int dt = 0; dt < 12; ++dt)
            accO[mt][dt] = (f32x4){0.f, 0.f, 0.f, 0.f};
    float lpart = 0.f;

    // A-frag base (elems): dG = 2*kf + (q>>1); lat = lt*16 + lr
    const int latg  = lt * 16 + lr;
    const int slotA = (latg >> 3) * 9 + (latg & 7);
    const int aBaseE = (q >> 1) * 560 + slotA * 16 + (q & 1) * 8;

    // tr-read base (bytes): dG0 = w*12; quad q covers lats 8q..8q+7
    const unsigned sbase =
        (unsigned)(size_t)(__attribute__((address_space(3))) unsigned short*)sLat;
    const unsigned bAddr = sbase + (unsigned)(w * 13440 + q * 288 + lr * 2);

    // Prologue: DMA tile 0 into LDS (13 full rounds + 32-chunk tail)
    {
        #pragma unroll
        for (int i = 0; i < 13; ++i)
            async_cp16(latb + ((size_t)i * 256 + tid) * 8,
                       sLat + (i * 256 + (tid & ~63)) * 8);
        if (tid < 32)
            async_cp16(latb + ((size_t)13 * 256 + tid) * 8,
                       sLat + (13 * 256) * 8);
    }
    __syncthreads();   // drain -> tile 0 ready

    for (int s = 0; s < NSTEP; ++s) {
        // ---- S^T phase: A from LDS (b128, conflict-free), Q in regs ----
        f32x4 sva = {0.f,0.f,0.f,0.f}, svb = {0.f,0.f,0.f,0.f};
        #pragma unroll
        for (int kp = 0; kp < 12; ++kp) {
            bf16x8 a0 = *(const bf16x8*)&sLat[aBaseE + (2 * kp)     * 1120];
            bf16x8 a1 = *(const bf16x8*)&sLat[aBaseE + (2 * kp + 1) * 1120];
            bf16x8 b0 = *(const bf16x8*)&qf[2 * kp];
            bf16x8 b1 = *(const bf16x8*)&qf[2 * kp + 1];
            sva = __builtin_amdgcn_mfma_f32_16x16x32_bf16(a0, b0, sva, 0, 0, 0);
            svb = __builtin_amdgcn_mfma_f32_16x16x32_bf16(a1, b1, svb, 0, 0, 0);
        }

        // ---- O-phase B frags from the SAME LDS tile via HW transpose read.
        // lane(lr,q): elem j = Lat[lat = 8q + j][d = w*192 + dt*16 + lr]
        u32x2 bLo[12], bHi[12];
        #pragma unroll
        for (int dt = 0; dt < 12; ++dt) {
            asm volatile("ds_read_b64_tr_b16 %0, %1 offset:%2"
                         : "=v"(bLo[dt]) : "v"(bAddr), "i"(dt * 1120));
            asm volatile("ds_read_b64_tr_b16 %0, %1 offset:%2"
                         : "=v"(bHi[dt]) : "v"(bAddr), "i"(dt * 1120 + 128));
        }

        // ---- exp (no max-sub), P write (one b64), l partial ----
        {
            const int lat0 = s * 32 + lt * 16 + q * 4;
            f32x4 sv = sva + svb;
            float e0 = (lat0     < KLAT) ? __expf(sv[0]) : 0.f;
            float e1 = (lat0 + 1 < KLAT) ? __expf(sv[1]) : 0.f;
            float e2 = (lat0 + 2 < KLAT) ? __expf(sv[2]) : 0.f;
            float e3 = (lat0 + 3 < KLAT) ? __expf(sv[3]) : 0.f;
            lpart += (e0 + e1) + (e2 + e3);
            unsigned int p01 = f2bf(e0) | (f2bf(e1) << 16);
            unsigned int p23 = f2bf(e2) | (f2bf(e3) << 16);
            *(uint2*)&sP[(tt * 16 + lr) * 40 + lt * 16 + q * 4] =
                make_uint2(p01, p23);
        }

        // All tr/A reads + sP write landed before the barrier (rule #18).
        asm volatile("s_waitcnt lgkmcnt(0)" ::: "memory");
        __builtin_amdgcn_sched_barrier(0);
        __syncthreads();   // sLat reads done everywhere; sP published

        // DMA next tile into sLat (drained at loop-end barrier, hidden by O)
        {
            int nt = (s + 1 < NSTEP) ? s + 1 : 0;
            const unsigned short* gs = latb + (size_t)nt * TILE_SH;
            #pragma unroll
            for (int i = 0; i < 13; ++i)
                async_cp16(gs + ((size_t)i * 256 + tid) * 8,
                           sLat + (i * 256 + (tid & ~63)) * 8);
            if (tid < 32)
                async_cp16(gs + ((size_t)13 * 256 + tid) * 8,
                           sLat + (13 * 256) * 8);
        }

        // ---- O phase: O[tok][d] += P[tok][lat] * Lat[lat][d] ----
        bf16x8 pA0 = *(const bf16x8*)&sP[lr * 40 + q * 8];
        bf16x8 pA1 = *(const bf16x8*)&sP[(16 + lr) * 40 + q * 8];
        #pragma unroll
        for (int dt = 0; dt < 12; ++dt) {
            uint4 bw = make_uint4(bLo[dt].x, bLo[dt].y, bHi[dt].x, bHi[dt].y);
            bf16x8 b = *(bf16x8*)&bw;
            accO[0][dt] = __builtin_amdgcn_mfma_f32_16x16x32_bf16(pA0, b, accO[0][dt], 0, 0, 0);
            accO[1][dt] = __builtin_amdgcn_mfma_f32_16x16x32_bf16(pA1, b, accO[1][dt], 0, 0, 0);
        }
        __syncthreads();   // drains DMA (tile s+1 ready); sP reads done
    }

    // softmax denominator: reduce over quads (token invariant under xor 16/32),
    // then cross-latTile sum via sL.
    lpart += __shfl_xor(lpart, 16, 64);
    lpart += __shfl_xor(lpart, 32, 64);
    if (lane < 16) sL[lt][tt * 16 + lane] = lpart;
    __syncthreads();

    // epilogue: /l + lang + special-token override, fp32 out
    #pragma unroll
    for (int mt = 0; mt < 2; ++mt) {
        int tl0 = mt * 16 + q * 4;
        float linv[4]; int fid[4];
        #pragma unroll
        for (int r = 0; r < 4; ++r) {
            linv[r] = 1.0f / (sL[0][tl0 + r] + sL[1][tl0 + r]);
            fid[r]  = x[(m0 + tl0 + r) * 8];
        }
        #pragma unroll
        for (int dt = 0; dt < 12; ++dt) {
            int d = w * 192 + dt * 16 + lr;
            #pragma unroll
            for (int r = 0; r < 4; ++r) {
                int tok = m0 + tl0 + r;
                float v = accO[mt][dt][r] * linv[r] + bf2f(langb[tok * DIM + d]);
                if (fid[r] < 4) v = cemb[fid[r] * DIM + d];  // PAD/CLS/SEP/UNK
                out[tok * DIM + d] = v;
            }
        }
    }
}

// ---------------------------------------------------------------------------
extern "C" void kernel_launch(void* const* d_in, const int* in_sizes, int n_in,
                              void* d_out, int out_size, void* d_ws, size_t ws_size,
                              hipStream_t stream) {
    const int*   x      = (const int*)d_in[0];     // (16,1024,8) int
    const float* cemb   = (const float*)d_in[1];   // (30000,768) f32
    const float* latent = (const float*)d_in[2];   // (5000,768) f32
    float* out = (float*)d_out;                    // (16,1024,768) f32

    unsigned short* langb = (unsigned short*)d_ws;              // 25.2 MB
    unsigned short* latb  = langb + (size_t)NTOK * DIM;         // 8.44 MB

    int nU = NSTEP * TCH;                // 16B chunks in latb
    cvt_latU<<<(nU + 255) / 256, 256, 0, stream>>>(latent, latb);
    build_lang<<<NTOK, 192, 0, stream>>>(x, cemb, langb);
    fused_sde<<<NTOK / TOKB, 256, 0, stream>>>(x, cemb, langb, latb, out);
}

// Round 3
// 582.762 us; speedup vs baseline: 1.1276x; 1.1276x over previous
//
#include <hip/hip_runtime.h>

// Problem constants
#define PAD_ID 0
#define NTOK   16384          // B*L = 16*1024
#define DIM    768
#define KLAT   5000
#define KPAD   5024           // 157*32, zero-padded latent rows
#define NSTEP  157            // 5024/32
#define TILE_SH 24576         // shorts per 32x768 tile (48 KB)
#define TOKB   64             // tokens per block (256 blocks -> 1 block/CU, 512 thr)

typedef float f32x4 __attribute__((ext_vector_type(4)));
typedef __bf16 bf16x8 __attribute__((ext_vector_type(8)));

__device__ __forceinline__ unsigned int f2bf(float f) {
    unsigned int u = __float_as_uint(f);
    u += 0x7fffu + ((u >> 16) & 1u);   // RNE
    return u >> 16;
}
__device__ __forceinline__ float bf2f(unsigned short h) {
    return __uint_as_float(((unsigned int)h) << 16);
}
__device__ __forceinline__ void async_cp16(const unsigned short* g, unsigned short* l) {
    __builtin_amdgcn_global_load_lds(
        (const __attribute__((address_space(1))) unsigned int*)g,
        (__attribute__((address_space(3))) unsigned int*)l, 16, 0, 0);
}

// ---------------------------------------------------------------------------
// Kernel 0a: latent -> latbS, bf16, MFMA-A-fragment order per 32-row tile:
//   latbS[t][kf][h][lane][j] = Lat[t*32 + h*16 + (lane&15)][kf*32 + (lane>>4)*8 + j]
// S-phase LDS image is then frag-linear: ds_read_b128 at stride-1, 0 conflicts.
// ---------------------------------------------------------------------------
__global__ __launch_bounds__(256) void cvt_latS(const float* __restrict__ latent,
                                                unsigned short* __restrict__ latbS) {
    int g = blockIdx.x * 256 + threadIdx.x;          // one 8-short frag per thread
    if (g >= NSTEP * 24 * 2 * 64) return;
    int lane = g & 63; int rest = g >> 6;            // [t][kf][h]
    int h = rest & 1;  int kfr = rest >> 1;
    int kf = kfr % 24; int t  = kfr / 24;
    int row = t * 32 + h * 16 + (lane & 15);
    int col = kf * 32 + (lane >> 4) * 8;
    float4 v0 = make_float4(0.f,0.f,0.f,0.f), v1 = v0;
    if (row < KLAT) {
        v0 = *(const float4*)(latent + (long)row * DIM + col);
        v1 = *(const float4*)(latent + (long)row * DIM + col + 4);
    }
    uint4 o;
    o.x = f2bf(v0.x) | (f2bf(v0.y) << 16);
    o.y = f2bf(v0.z) | (f2bf(v0.w) << 16);
    o.z = f2bf(v1.x) | (f2bf(v1.y) << 16);
    o.w = f2bf(v1.z) | (f2bf(v1.w) << 16);
    *(uint4*)(latbS + (size_t)g * 8) = o;
}

// ---------------------------------------------------------------------------
// Kernel 0b: latent -> latbT, bf16, d-major per tile:
//   latbT[t][d][kk] = Lat[t*32 + kk][d]   (tile = 768x32 = 48 KB)
// O-phase B-frags become fully-coalesced global dwordx4 direct to registers.
// ---------------------------------------------------------------------------
__global__ __launch_bounds__(256) void cvt_latT(const float* __restrict__ latent,
                                                unsigned short* __restrict__ latbT) {
    int g = blockIdx.x * 256 + threadIdx.x;          // one 8-short group
    if (g >= NSTEP * DIM * 4) return;
    int kk8 = g & 3; int rest = g >> 2;
    int d = rest % DIM; int t = rest / DIM;
    int kk0 = kk8 * 8;
    unsigned short v[8];
    #pragma unroll
    for (int j = 0; j < 8; ++j) {
        int row = t * 32 + kk0 + j;
        v[j] = (row < KLAT) ? (unsigned short)f2bf(latent[(long)row * DIM + d])
                            : (unsigned short)0;
    }
    *(uint4*)(latbT + (size_t)g * 8) = *(uint4*)v;
}

// ---------------------------------------------------------------------------
// Kernel 1: lang_emb = tanh(masked-mean of char embeddings), stored bf16.
// ---------------------------------------------------------------------------
__global__ __launch_bounds__(192) void build_lang(const int* __restrict__ x,
                                                  const float* __restrict__ cemb,
                                                  unsigned short* __restrict__ langb) {
    int tok = blockIdx.x;
    int t = threadIdx.x;
    const int* xs = x + tok * 8;
    int ids[8]; int cnt = 0;
    #pragma unroll
    for (int c = 0; c < 8; ++c) { ids[c] = xs[c]; cnt += (ids[c] != PAD_ID); }
    float4 acc = make_float4(0.f, 0.f, 0.f, 0.f);
    #pragma unroll
    for (int c = 0; c < 8; ++c) {
        if (ids[c] != PAD_ID) {
            float4 v = *(const float4*)(cemb + (long)ids[c] * DIM + t * 4);
            acc.x += v.x; acc.y += v.y; acc.z += v.z; acc.w += v.w;
        }
    }
    float cntf = (float)max(cnt, 1);
    unsigned int u0 = f2bf(tanhf(acc.x / cntf)) | (f2bf(tanhf(acc.y / cntf)) << 16);
    unsigned int u1 = f2bf(tanhf(acc.z / cntf)) | (f2bf(tanhf(acc.w / cntf)) << 16);
    *(uint2*)(langb + tok * DIM + t * 4) = make_uint2(u0, u1);
}

// ---------------------------------------------------------------------------
// Kernel 2 (v4): ONE 512-thread block per CU (256 blocks). The two v2 blocks
// merged -> the latbS DMA and latbT bO streams are read ONCE per CU per step
// (cache traffic halves). sLat and sP are double-buffered (LDS = 107 KB, all
// ours at 1 block/CU) -> ONE __syncthreads per step:
//   [DMA(s+1)->buf[c^1] | bO loads | S-phase reads buf[c] | exp -> sP[c]]
//   B(s)  [O-phase reads sP[c]]
// Hazards: S-reads(s-1) of buf[c^1] < B(s-1) <= DMA-issue(s+1);
//          O-reads(s) of sP[c] < B(s+1) <= sP[c] rewrite at step s+2.
// Wave roles: S-phase (tt=w&3, lt=w>>2): 16tok x 16lat; O-phase: wave w owns
// d-range w*96 for all 64 tokens (accO[4][6] = 96 regs).
// ---------------------------------------------------------------------------
__global__ __launch_bounds__(512, 2) void fused_sde(
        const int* __restrict__ x, const float* __restrict__ cemb,
        const unsigned short* __restrict__ langb,
        const unsigned short* __restrict__ latbS,
        const unsigned short* __restrict__ latbT,
        float* __restrict__ out) {
    __shared__ unsigned short sLat[2][TILE_SH];   // 2 x 48 KB, frag-linear
    __shared__ unsigned short sP[2][TOKB * 40];   // 2 x 5 KB, row-padded (+8)
    __shared__ float sL[2][TOKB];

    const int tid  = threadIdx.x;
    const int w    = tid >> 6;
    const int lane = tid & 63;
    const int lr   = lane & 15;
    const int q    = lane >> 4;
    const int tt   = w & 3;          // S-phase token tile (0..3)
    const int lt   = w >> 2;         // S-phase lat tile (0..1)
    const int m0   = blockIdx.x * TOKB;

    // Q fragments (B-operand for S^T): token = m0 + tt*16 + lr
    uint4 qf[24];
    {
        const unsigned short* qr = langb + (m0 + tt * 16 + lr) * DIM;
        #pragma unroll
        for (int kf = 0; kf < 24; ++kf)
            qf[kf] = *(const uint4*)(qr + kf * 32 + q * 8);
    }

    f32x4 accO[4][6];
    #pragma unroll
    for (int mt = 0; mt < 4; ++mt)
        #pragma unroll
        for (int dt = 0; dt < 6; ++dt)
            accO[mt][dt] = (f32x4){0.f, 0.f, 0.f, 0.f};
    float lpart = 0.f;

    const int aBase = lt * 64 + lane;                 // A-frag slot within kf
    const int bBase = (w * 96 + lr) * 32 + q * 8;     // latbT frag base

    // Prologue: DMA tile 0 into buf 0 (3072 chunks = 512 thr x 6)
    #pragma unroll
    for (int i = 0; i < 6; ++i)
        async_cp16(latbS + ((size_t)i * 512 + tid) * 8,
                   &sLat[0][(i * 512 + (tid & ~63)) * 8]);
    __syncthreads();   // drain -> tile 0 ready

    for (int s = 0; s < NSTEP; ++s) {
        const int c = s & 1;

        // DMA next tile into the other buffer (lands during S-phase)
        {
            int nt = (s + 1 < NSTEP) ? s + 1 : 0;
            const unsigned short* gs = latbS + (size_t)nt * TILE_SH;
            #pragma unroll
            for (int i = 0; i < 6; ++i)
                async_cp16(gs + ((size_t)i * 512 + tid) * 8,
                           &sLat[c ^ 1][(i * 512 + (tid & ~63)) * 8]);
        }

        // O-phase B frags, round 1 (dt 0..2): hidden under S-phase
        const unsigned short* bt = latbT + (size_t)s * TILE_SH;
        uint4 bO0[3], bO1[3];
        #pragma unroll
        for (int dt = 0; dt < 3; ++dt)
            bO0[dt] = *(const uint4*)(bt + bBase + dt * 512);

        // ---- S^T phase: A from sLat[c] (b128, conflict-free), Q in regs ----
        f32x4 sva = {0.f,0.f,0.f,0.f}, svb = {0.f,0.f,0.f,0.f};
        #pragma unroll
        for (int kp = 0; kp < 12; ++kp) {
            bf16x8 a0 = *(const bf16x8*)&sLat[c][((2 * kp)     * 128 + aBase) * 8];
            bf16x8 a1 = *(const bf16x8*)&sLat[c][((2 * kp + 1) * 128 + aBase) * 8];
            bf16x8 b0 = *(const bf16x8*)&qf[2 * kp];
            bf16x8 b1 = *(const bf16x8*)&qf[2 * kp + 1];
            sva = __builtin_amdgcn_mfma_f32_16x16x32_bf16(a0, b0, sva, 0, 0, 0);
            svb = __builtin_amdgcn_mfma_f32_16x16x32_bf16(a1, b1, svb, 0, 0, 0);
        }

        // round 2 (dt 3..5)
        #pragma unroll
        for (int dt = 0; dt < 3; ++dt)
            bO1[dt] = *(const uint4*)(bt + bBase + (dt + 3) * 512);

        // ---- exp (no max-sub; |s|=O(1)), P write (one b64), l partial ----
        {
            const int lat0 = s * 32 + lt * 16 + q * 4;
            f32x4 sv = sva + svb;
            float e0 = (lat0     < KLAT) ? __expf(sv[0]) : 0.f;
            float e1 = (lat0 + 1 < KLAT) ? __expf(sv[1]) : 0.f;
            float e2 = (lat0 + 2 < KLAT) ? __expf(sv[2]) : 0.f;
            float e3 = (lat0 + 3 < KLAT) ? __expf(sv[3]) : 0.f;
            lpart += (e0 + e1) + (e2 + e3);
            unsigned int p01 = f2bf(e0) | (f2bf(e1) << 16);
            unsigned int p23 = f2bf(e2) | (f2bf(e3) << 16);
            *(uint2*)&sP[c][(tt * 16 + lr) * 40 + lt * 16 + q * 4] =
                make_uint2(p01, p23);
        }

        __syncthreads();   // ONE barrier: sP[c] published; DMA(s+1) drained

        // ---- O phase: O[tok][d] += P[tok][lat] * Lat[lat][d] ----
        bf16x8 pA[4];
        #pragma unroll
        for (int mt = 0; mt < 4; ++mt)
            pA[mt] = *(const bf16x8*)&sP[c][(mt * 16 + lr) * 40 + q * 8];
        #pragma unroll
        for (int dt = 0; dt < 3; ++dt) {
            bf16x8 b = *(const bf16x8*)&bO0[dt];
            #pragma unroll
            for (int mt = 0; mt < 4; ++mt)
                accO[mt][dt] = __builtin_amdgcn_mfma_f32_16x16x32_bf16(
                    pA[mt], b, accO[mt][dt], 0, 0, 0);
        }
        #pragma unroll
        for (int dt = 0; dt < 3; ++dt) {
            bf16x8 b = *(const bf16x8*)&bO1[dt];
            #pragma unroll
            for (int mt = 0; mt < 4; ++mt)
                accO[mt][dt + 3] = __builtin_amdgcn_mfma_f32_16x16x32_bf16(
                    pA[mt], b, accO[mt][dt + 3], 0, 0, 0);
        }
        // no trailing barrier: next step writes sLat[c^1] (S-reads done at B)
        // and sP[c^1]; sP[c] reads above complete before this wave's B(s+1).
    }

    // softmax denominator: reduce over quads (token invariant under xor 16/32),
    // then cross-latTile sum via sL.
    lpart += __shfl_xor(lpart, 16, 64);
    lpart += __shfl_xor(lpart, 32, 64);
    if (lane < 16) sL[lt][tt * 16 + lane] = lpart;
    __syncthreads();

    // epilogue: /l + lang + special-token override, fp32 out
    #pragma unroll
    for (int mt = 0; mt < 4; ++mt) {
        int tl0 = mt * 16 + q * 4;
        float linv[4]; int fid[4];
        #pragma unroll
        for (int r = 0; r < 4; ++r) {
            linv[r] = 1.0f / (sL[0][tl0 + r] + sL[1][tl0 + r]);
            fid[r]  = x[(m0 + tl0 + r) * 8];
        }
        #pragma unroll
        for (int dt = 0; dt < 6; ++dt) {
            int d = w * 96 + dt * 16 + lr;
            #pragma unroll
            for (int r = 0; r < 4; ++r) {
                int tok = m0 + tl0 + r;
                float v = accO[mt][dt][r] * linv[r] + bf2f(langb[tok * DIM + d]);
                if (fid[r] < 4) v = cemb[fid[r] * DIM + d];  // PAD/CLS/SEP/UNK
                out[tok * DIM + d] = v;
            }
        }
    }
}

// ---------------------------------------------------------------------------
extern "C" void kernel_launch(void* const* d_in, const int* in_sizes, int n_in,
                              void* d_out, int out_size, void* d_ws, size_t ws_size,
                              hipStream_t stream) {
    const int*   x      = (const int*)d_in[0];     // (16,1024,8) int
    const float* cemb   = (const float*)d_in[1];   // (30000,768) f32
    const float* latent = (const float*)d_in[2];   // (5000,768) f32
    float* out = (float*)d_out;                    // (16,1024,768) f32

    unsigned short* langb = (unsigned short*)d_ws;                  // 25.2 MB
    unsigned short* latbS = langb + (size_t)NTOK * DIM;             // 7.7 MB
    unsigned short* latbT = latbS + (size_t)NSTEP * TILE_SH;        // 7.7 MB

    int nS = NSTEP * 24 * 2 * 64;        // frag groups in latbS
    int nT = NSTEP * DIM * 4;            // 8-short groups in latbT
    cvt_latS<<<(nS + 255) / 256, 256, 0, stream>>>(latent, latbS);
    cvt_latT<<<(nT + 255) / 256, 256, 0, stream>>>(latent, latbT);
    build_lang<<<NTOK, 192, 0, stream>>>(x, cemb, langb);
    fused_sde<<<NTOK / TOKB, 512, 0, stream>>>(x, cemb, langb, latbS, latbT, out);
}

// Round 4
// 582.563 us; speedup vs baseline: 1.1280x; 1.0003x over previous
//
#include <hip/hip_runtime.h>

// Problem constants
#define PAD_ID 0
#define NTOK   16384          // B*L = 16*1024
#define DIM    768
#define KLAT   5000
#define NSTEP  157            // ceil(5024/32)
#define TILE_SH 24576         // shorts per 32x768 tile (48 KB)
#define TOKB   64             // tokens per block (256 blocks, 512 threads)

typedef float  f32x4  __attribute__((ext_vector_type(4)));
typedef float  f32x16 __attribute__((ext_vector_type(16)));
typedef __bf16 bf16x8 __attribute__((ext_vector_type(8)));

__device__ __forceinline__ unsigned int f2bf(float f) {
    unsigned int u = __float_as_uint(f);
    u += 0x7fffu + ((u >> 16) & 1u);   // RNE
    return u >> 16;
}
__device__ __forceinline__ float bf2f(unsigned short h) {
    return __uint_as_float(((unsigned int)h) << 16);
}
__device__ __forceinline__ void async_cp16(const unsigned short* g, unsigned short* l) {
    __builtin_amdgcn_global_load_lds(
        (const __attribute__((address_space(1))) unsigned int*)g,
        (__attribute__((address_space(3))) unsigned int*)l, 16, 0, 0);
}
__device__ __forceinline__ void barrier_mid() {   // LDS-only barrier: DMA stays in flight
    asm volatile("s_waitcnt lgkmcnt(0)" ::: "memory");
    __builtin_amdgcn_sched_barrier(0);
    __builtin_amdgcn_s_barrier();
    __builtin_amdgcn_sched_barrier(0);
}

// ---------------------------------------------------------------------------
// Kernel 0a: latent -> latbS, bf16, 32x32x16 A-fragment order per 32-row tile:
//   latbS[t][kb][lane][j] = Lat[t*32 + (lane&31)][kb*16 + (lane>>5)*8 + j]
// (kb = 0..47). Frag-linear: S-phase ds_read_b128 stride-1, 0 conflicts.
// ---------------------------------------------------------------------------
__global__ __launch_bounds__(256) void cvt_latS(const float* __restrict__ latent,
                                                unsigned short* __restrict__ latbS) {
    int g = blockIdx.x * 256 + threadIdx.x;          // one 8-short frag per thread
    if (g >= NSTEP * 48 * 64) return;
    int lane = g & 63; int rest = g >> 6;
    int kb = rest % 48; int t = rest / 48;
    int row = t * 32 + (lane & 31);
    int col = kb * 16 + (lane >> 5) * 8;
    float4 v0 = make_float4(0.f,0.f,0.f,0.f), v1 = v0;
    if (row < KLAT) {
        v0 = *(const float4*)(latent + (long)row * DIM + col);
        v1 = *(const float4*)(latent + (long)row * DIM + col + 4);
    }
    uint4 o;
    o.x = f2bf(v0.x) | (f2bf(v0.y) << 16);
    o.y = f2bf(v0.z) | (f2bf(v0.w) << 16);
    o.z = f2bf(v1.x) | (f2bf(v1.y) << 16);
    o.w = f2bf(v1.z) | (f2bf(v1.w) << 16);
    *(uint4*)(latbS + (size_t)g * 8) = o;
}

// ---------------------------------------------------------------------------
// Kernel 0b: latent -> latbT, bf16, d-major per tile:
//   latbT[t][d][kk] = Lat[t*32 + kk][d]   (tile = 768x32 = 48 KB)
// O-phase B-frags are coalesced global dwordx4 direct to registers.
// ---------------------------------------------------------------------------
__global__ __launch_bounds__(256) void cvt_latT(const float* __restrict__ latent,
                                                unsigned short* __restrict__ latbT) {
    int g = blockIdx.x * 256 + threadIdx.x;          // one 8-short group
    if (g >= NSTEP * DIM * 4) return;
    int kk8 = g & 3; int rest = g >> 2;
    int d = rest % DIM; int t = rest / DIM;
    int kk0 = kk8 * 8;
    unsigned short v[8];
    #pragma unroll
    for (int j = 0; j < 8; ++j) {
        int row = t * 32 + kk0 + j;
        v[j] = (row < KLAT) ? (unsigned short)f2bf(latent[(long)row * DIM + d])
                            : (unsigned short)0;
    }
    *(uint4*)(latbT + (size_t)g * 8) = *(uint4*)v;
}

// ---------------------------------------------------------------------------
// Kernel 1: lang_emb = tanh(masked-mean of char embeddings), stored bf16.
// ---------------------------------------------------------------------------
__global__ __launch_bounds__(192) void build_lang(const int* __restrict__ x,
                                                  const float* __restrict__ cemb,
                                                  unsigned short* __restrict__ langb) {
    int tok = blockIdx.x;
    int t = threadIdx.x;
    const int* xs = x + tok * 8;
    int ids[8]; int cnt = 0;
    #pragma unroll
    for (int c = 0; c < 8; ++c) { ids[c] = xs[c]; cnt += (ids[c] != PAD_ID); }
    float4 acc = make_float4(0.f, 0.f, 0.f, 0.f);
    #pragma unroll
    for (int c = 0; c < 8; ++c) {
        if (ids[c] != PAD_ID) {
            float4 v = *(const float4*)(cemb + (long)ids[c] * DIM + t * 4);
            acc.x += v.x; acc.y += v.y; acc.z += v.z; acc.w += v.w;
        }
    }
    float cntf = (float)max(cnt, 1);
    unsigned int u0 = f2bf(tanhf(acc.x / cntf)) | (f2bf(tanhf(acc.y / cntf)) << 16);
    unsigned int u1 = f2bf(tanhf(acc.z / cntf)) | (f2bf(tanhf(acc.w / cntf)) << 16);
    *(uint2*)(langb + tok * DIM + t * 4) = make_uint2(u0, u1);
}

// ---------------------------------------------------------------------------
// Kernel 2 (v5): 512-thread block, 256 blocks (1/CU). S-phase uses 32x32x16
// MFMA (halves LDS A-frag reads to 96/CU-step); wave = (tile=w&1, ks=w>>1):
// K-split 192 each, partials exchanged via frag-linear pbuf. O(s-1) runs
// software-pipelined around B_mid of step s (pure-reg MFMA, setprio'd).
// Per iter:  [DMA(s+1) | bO(s-1) | pA(s-1) | O-part-A(mt0,1) | S(s) | pbuf]
//            B_mid(lgkm only)  [reduce+exp -> sPf | O-part-B(mt2,3)]  B_end.
// ---------------------------------------------------------------------------
__global__ __launch_bounds__(512, 2) void fused_sde(
        const int* __restrict__ x, const float* __restrict__ cemb,
        const unsigned short* __restrict__ langb,
        const unsigned short* __restrict__ latbS,
        const unsigned short* __restrict__ latbT,
        float* __restrict__ out) {
    __shared__ unsigned short sLat[2][TILE_SH];     // 96 KB, frag-linear A
    __shared__ unsigned short sPf[2][4 * 64 * 8];   // 8 KB, P in O-A-frag order
    __shared__ float pbuf[2][4][4][64][4];          // 32 KB, S partial quads
    __shared__ float sL[2][4][32];                  // denominator partials

    const int tid  = threadIdx.x;
    const int w    = tid >> 6;
    const int lane = tid & 63;
    const int lr   = lane & 15;
    const int q    = lane >> 4;
    const int l31  = lane & 31;
    const int h    = lane >> 5;
    const int tile = w & 1;          // S: token tile (32 toks)
    const int ks   = w >> 1;         // S: K-slice (192 of 768)
    const int m0   = blockIdx.x * TOKB;

    // Q fragments (B-operand, 32x32x16): lane holds Q[tile*32+l31][ks*192+kb*16+h*8+j]
    uint4 qf[12];
    {
        const unsigned short* qr =
            langb + (size_t)(m0 + tile * 32 + l31) * DIM + ks * 192 + h * 8;
        #pragma unroll
        for (int kb = 0; kb < 12; ++kb)
            qf[kb] = *(const uint4*)(qr + kb * 16);
    }

    f32x4 accO[4][6];
    #pragma unroll
    for (int mt = 0; mt < 4; ++mt)
        #pragma unroll
        for (int dt = 0; dt < 6; ++dt)
            accO[mt][dt] = (f32x4){0.f, 0.f, 0.f, 0.f};
    float lpart = 0.f;

    const int aBase = lane * 8;                    // shorts within a kb block
    const int bBase = (w * 96 + lr) * 32 + q * 8;  // latbT frag base

    // Prologue: DMA tile 0 -> buf 0
    #pragma unroll
    for (int i = 0; i < 6; ++i)
        async_cp16(latbS + ((size_t)i * 512 + tid) * 8,
                   &sLat[0][(i * 512 + (tid & ~63)) * 8]);
    __syncthreads();

    // ---- peeled iteration s = 0 (S only) ----
    {
        #pragma unroll
        for (int i = 0; i < 6; ++i)       // DMA tile 1 -> buf 1
            async_cp16(latbS + (size_t)TILE_SH + ((size_t)i * 512 + tid) * 8,
                       &sLat[1][(i * 512 + (tid & ~63)) * 8]);
        f32x16 sacc;
        #pragma unroll
        for (int i = 0; i < 16; ++i) sacc[i] = 0.f;
        #pragma unroll
        for (int kb = 0; kb < 12; ++kb) {
            bf16x8 a = *(const bf16x8*)&sLat[0][(ks * 12 + kb) * 512 + aBase];
            sacc = __builtin_amdgcn_mfma_f32_32x32x16_bf16(
                a, *(const bf16x8*)&qf[kb], sacc, 0, 0, 0);
        }
        f32x4 own;
        #pragma unroll
        for (int g = 0; g < 4; ++g) {
            f32x4 qv = {sacc[4*g+0], sacc[4*g+1], sacc[4*g+2], sacc[4*g+3]};
            if (g == ks) own = qv;
            else *(f32x4*)&pbuf[tile][ks][g][lane][0] = qv;
        }
        barrier_mid();
        #pragma unroll
        for (int p = 0; p < 4; ++p)
            if (p != ks) own += *(const f32x4*)&pbuf[tile][p][ks][lane][0];
        // exp + pack into sPf[0]
        {
            const int lat0 = 0 * 32 + ks * 8 + h * 4;
            float e0 = (lat0     < KLAT) ? __expf(own[0]) : 0.f;
            float e1 = (lat0 + 1 < KLAT) ? __expf(own[1]) : 0.f;
            float e2 = (lat0 + 2 < KLAT) ? __expf(own[2]) : 0.f;
            float e3 = (lat0 + 3 < KLAT) ? __expf(own[3]) : 0.f;
            lpart += (e0 + e1) + (e2 + e3);
            int mt = tile * 2 + (l31 >> 4);
            *(uint2*)&sPf[0][(mt * 64 + lr + 16 * ks) * 8 + 4 * h] =
                make_uint2(f2bf(e0) | (f2bf(e1) << 16), f2bf(e2) | (f2bf(e3) << 16));
        }
        __syncthreads();
    }

    // ---- main loop: iteration s does S(s) and O(s-1) ----
    for (int s = 1; s < NSTEP; ++s) {
        const int c = s & 1;
        {   // DMA(s+1) -> buf[c^1] (drained at this iter's end barrier)
            int nt = (s + 1 < NSTEP) ? s + 1 : 0;
            const unsigned short* gs = latbS + (size_t)nt * TILE_SH;
            #pragma unroll
            for (int i = 0; i < 6; ++i)
                async_cp16(gs + ((size_t)i * 512 + tid) * 8,
                           &sLat[c ^ 1][(i * 512 + (tid & ~63)) * 8]);
        }
        // B-frags of Lat tile (s-1) for O(s-1), coalesced global->reg
        const unsigned short* bt = latbT + (size_t)(s - 1) * TILE_SH;
        uint4 bO[6];
        #pragma unroll
        for (int dt = 0; dt < 6; ++dt)
            bO[dt] = *(const uint4*)(bt + bBase + dt * 512);
        // P(s-1) A-frags
        bf16x8 pA[4];
        #pragma unroll
        for (int mt = 0; mt < 4; ++mt)
            pA[mt] = *(const bf16x8*)&sPf[c ^ 1][(mt * 64 + lane) * 8];

        // ---- O-part-A: mt 0,1 (pure reg MFMA) ----
        __builtin_amdgcn_s_setprio(1);
        #pragma unroll
        for (int dt = 0; dt < 6; ++dt) {
            bf16x8 b = *(const bf16x8*)&bO[dt];
            accO[0][dt] = __builtin_amdgcn_mfma_f32_16x16x32_bf16(pA[0], b, accO[0][dt], 0, 0, 0);
            accO[1][dt] = __builtin_amdgcn_mfma_f32_16x16x32_bf16(pA[1], b, accO[1][dt], 0, 0, 0);
        }
        __builtin_amdgcn_s_setprio(0);

        // ---- S(s): 12 x mfma_32x32x16, A from sLat[c], B = qf regs ----
        f32x16 sacc;
        #pragma unroll
        for (int i = 0; i < 16; ++i) sacc[i] = 0.f;
        #pragma unroll
        for (int kb = 0; kb < 12; ++kb) {
            bf16x8 a = *(const bf16x8*)&sLat[c][(ks * 12 + kb) * 512 + aBase];
            sacc = __builtin_amdgcn_mfma_f32_32x32x16_bf16(
                a, *(const bf16x8*)&qf[kb], sacc, 0, 0, 0);
        }
        f32x4 own;
        #pragma unroll
        for (int g = 0; g < 4; ++g) {
            f32x4 qv = {sacc[4*g+0], sacc[4*g+1], sacc[4*g+2], sacc[4*g+3]};
            if (g == ks) own = qv;
            else *(f32x4*)&pbuf[tile][ks][g][lane][0] = qv;
        }

        barrier_mid();   // LDS drained & synced; DMA still in flight

        // ---- reduce partials, exp, publish P(s) ----
        #pragma unroll
        for (int p = 0; p < 4; ++p)
            if (p != ks) own += *(const f32x4*)&pbuf[tile][p][ks][lane][0];
        {
            const int lat0 = s * 32 + ks * 8 + h * 4;
            float e0 = (lat0     < KLAT) ? __expf(own[0]) : 0.f;
            float e1 = (lat0 + 1 < KLAT) ? __expf(own[1]) : 0.f;
            float e2 = (lat0 + 2 < KLAT) ? __expf(own[2]) : 0.f;
            float e3 = (lat0 + 3 < KLAT) ? __expf(own[3]) : 0.f;
            lpart += (e0 + e1) + (e2 + e3);
            int mt = tile * 2 + (l31 >> 4);
            *(uint2*)&sPf[c][(mt * 64 + lr + 16 * ks) * 8 + 4 * h] =
                make_uint2(f2bf(e0) | (f2bf(e1) << 16), f2bf(e2) | (f2bf(e3) << 16));
        }

        // ---- O-part-B: mt 2,3 ----
        __builtin_amdgcn_s_setprio(1);
        #pragma unroll
        for (int dt = 0; dt < 6; ++dt) {
            bf16x8 b = *(const bf16x8*)&bO[dt];
            accO[2][dt] = __builtin_amdgcn_mfma_f32_16x16x32_bf16(pA[2], b, accO[2][dt], 0, 0, 0);
            accO[3][dt] = __builtin_amdgcn_mfma_f32_16x16x32_bf16(pA[3], b, accO[3][dt], 0, 0, 0);
        }
        __builtin_amdgcn_s_setprio(0);

        __syncthreads();   // drains DMA(s+1); sPf[c] visible next iter
    }

    // ---- epilogue O(NSTEP-1): P in sPf[(NSTEP-1)&1 = 0] ----
    {
        const unsigned short* bt = latbT + (size_t)(NSTEP - 1) * TILE_SH;
        uint4 bO[6];
        #pragma unroll
        for (int dt = 0; dt < 6; ++dt)
            bO[dt] = *(const uint4*)(bt + bBase + dt * 512);
        bf16x8 pA[4];
        #pragma unroll
        for (int mt = 0; mt < 4; ++mt)
            pA[mt] = *(const bf16x8*)&sPf[0][(mt * 64 + lane) * 8];
        #pragma unroll
        for (int dt = 0; dt < 6; ++dt) {
            bf16x8 b = *(const bf16x8*)&bO[dt];
            #pragma unroll
            for (int mt = 0; mt < 4; ++mt)
                accO[mt][dt] = __builtin_amdgcn_mfma_f32_16x16x32_bf16(
                    pA[mt], b, accO[mt][dt], 0, 0, 0);
        }
    }

    // softmax denominator: lane l and l^32 share a token (other h half)
    lpart += __shfl_xor(lpart, 32, 64);
    if (lane < 32) sL[tile][ks][lane] = lpart;
    __syncthreads();

    // epilogue: /l + lang + special-token override, fp32 out
    #pragma unroll
    for (int mt = 0; mt < 4; ++mt) {
        int tl0 = mt * 16 + q * 4;
        float linv[4]; int fid[4];
        #pragma unroll
        for (int r = 0; r < 4; ++r) {
            int tok = tl0 + r;
            float den = sL[tok >> 5][0][tok & 31] + sL[tok >> 5][1][tok & 31] +
                        sL[tok >> 5][2][tok & 31] + sL[tok >> 5][3][tok & 31];
            linv[r] = 1.0f / den;
            fid[r]  = x[(m0 + tok) * 8];
        }
        #pragma unroll
        for (int dt = 0; dt < 6; ++dt) {
            int d = w * 96 + dt * 16 + lr;
            #pragma unroll
            for (int r = 0; r < 4; ++r) {
                int tok = m0 + tl0 + r;
                float v = accO[mt][dt][r] * linv[r] + bf2f(langb[tok * DIM + d]);
                if (fid[r] < 4) v = cemb[fid[r] * DIM + d];  // PAD/CLS/SEP/UNK
                out[tok * DIM + d] = v;
            }
        }
    }
}

// ---------------------------------------------------------------------------
extern "C" void kernel_launch(void* const* d_in, const int* in_sizes, int n_in,
                              void* d_out, int out_size, void* d_ws, size_t ws_size,
                              hipStream_t stream) {
    const int*   x      = (const int*)d_in[0];     // (16,1024,8) int
    const float* cemb   = (const float*)d_in[1];   // (30000,768) f32
    const float* latent = (const float*)d_in[2];   // (5000,768) f32
    float* out = (float*)d_out;                    // (16,1024,768) f32

    unsigned short* langb = (unsigned short*)d_ws;                  // 25.2 MB
    unsigned short* latbS = langb + (size_t)NTOK * DIM;             // 7.7 MB
    unsigned short* latbT = latbS + (size_t)NSTEP * TILE_SH;        // 7.7 MB

    int nS = NSTEP * 48 * 64;            // frag groups in latbS
    int nT = NSTEP * DIM * 4;            // 8-short groups in latbT
    cvt_latS<<<(nS + 255) / 256, 256, 0, stream>>>(latent, latbS);
    cvt_latT<<<(nT + 255) / 256, 256, 0, stream>>>(latent, latbT);
    build_lang<<<NTOK, 192, 0, stream>>>(x, cemb, langb);
    fused_sde<<<NTOK / TOKB, 512, 0, stream>>>(x, cemb, langb, latbS, latbT, out);
}